// Round 2
// baseline (200.826 us; speedup 1.0000x reference)
//
#include <hip/hip_runtime.h>
#include <math.h>

// Fused kernel: one block per row.
//  Phase 1: copy lprobs row -> out row (float4 bulk; scalar head/tail because
//           row stride V=50257 floats is not 16B-aligned across rows).
//  Phase 2 (after __syncthreads): scan the step-n+2 windows of the token row,
//           compare against the trailing (n-1)-gram, scatter -inf at banned
//           token positions within this row. Intra-block barrier gives the
//           copy->scatter ordering without a second kernel dispatch.
// Scalars (bsz/step/beam/n) live in device memory (graph capture forbids host
// sync reads), so R/S/V are derived on-device from the flat element counts.
__global__ void __launch_bounds__(1024)
ngram_fused_kernel(const int* __restrict__ tokens,
                   const float* __restrict__ lprobs,
                   float* __restrict__ out,
                   const int* __restrict__ bsz_p,
                   const int* __restrict__ step_p,
                   const int* __restrict__ beam_p,
                   const int* __restrict__ n_p,
                   long long tok_elems, long long lp_elems) {
    const int bsz  = *bsz_p;
    const int step = *step_p;
    const int beam = *beam_p;
    const int n    = *n_p;

    const int R = bsz * beam;
    const long long S = tok_elems / R;
    const long long V = lp_elems / R;

    const int tid = threadIdx.x;
    const int nt  = blockDim.x;

    for (int r = blockIdx.x; r < R; r += gridDim.x) {
        const long long base = (long long)r * V;
        const long long end  = base + V;
        const long long a    = (base + 3) & ~3LL;  // first 16B-aligned float idx
        const long long b    = end & ~3LL;         // last aligned boundary

        // head scalars (<4)
        for (long long i = base + tid; i < a; i += nt) out[i] = lprobs[i];
        // bulk float4
        {
            const float4* __restrict__ in4  = (const float4*)(lprobs + a);
            float4* __restrict__       out4 = (float4*)(out + a);
            const long long nv = (b - a) >> 2;
            #pragma unroll 4
            for (long long i = tid; i < nv; i += nt) out4[i] = in4[i];
        }
        // tail scalars (<4)
        for (long long i = b + tid; i < end; i += nt) out[i] = lprobs[i];

        __syncthreads();

        // scan windows + scatter -inf
        const int num_windows = step - n + 2;
        const int last_start  = step - n + 2;
        const int L = n - 1;
        const int* __restrict__ trow = tokens + (long long)r * S;
        for (int j = tid; j < num_windows; j += nt) {
            bool m = true;
            #pragma unroll 4
            for (int k = 0; k < L; ++k) m &= (trow[j + k] == trow[last_start + k]);
            if (m) {
                const int banned = trow[j + n - 1];
                out[base + banned] = -INFINITY;
            }
        }
        __syncthreads();  // keep rows independent if a block loops over >1 row
    }
}

extern "C" void kernel_launch(void* const* d_in, const int* in_sizes, int n_in,
                              void* d_out, int out_size, void* d_ws, size_t ws_size,
                              hipStream_t stream) {
    const int*   tokens = (const int*)d_in[0];
    const float* lprobs = (const float*)d_in[1];
    const int*   bsz_p  = (const int*)d_in[2];
    const int*   step_p = (const int*)d_in[3];
    const int*   beam_p = (const int*)d_in[4];
    const int*   n_p    = (const int*)d_in[5];
    float* out = (float*)d_out;

    // One block per row; R is device-side (bsz*beam), so launch a fixed grid
    // of 512 with a row-stride loop (R == 512 for this shape; loop covers
    // any mismatch safely).
    const int blocks = 512;
    const int block  = 1024;
    ngram_fused_kernel<<<blocks, block, 0, stream>>>(
        tokens, lprobs, out, bsz_p, step_p, beam_p, n_p,
        (long long)in_sizes[0], (long long)in_sizes[1]);
}